// Round 1
// baseline (2188.816 us; speedup 1.0000x reference)
//
#include <hip/hip_runtime.h>
#include <cstdint>
#include <cstddef>

#define FDIM 128
#define CLSN 10

// ---------------- degree / count ----------------
__global__ void deg_cnt_kernel(const int* __restrict__ src, const int* __restrict__ dst,
                               int* __restrict__ deg, int* __restrict__ cnt, int E) {
  int e = blockIdx.x * blockDim.x + threadIdx.x;
  if (e < E) {
    atomicAdd(&deg[src[e]], 1);
    atomicAdd(&cnt[dst[e]], 1);
  }
}

__global__ void dinv_kernel(const int* __restrict__ deg, float* __restrict__ dinv, int n) {
  int i = blockIdx.x * blockDim.x + threadIdx.x;
  if (i < n) {
    int d = deg[i];
    dinv[i] = d > 0 ? rsqrtf((float)d) : 0.0f;
  }
}

// ---------------- exclusive scan (single block, 1024 threads) ----------------
__global__ void scan_kernel(const int* __restrict__ cnt, int* __restrict__ rowptr, int n) {
  __shared__ int ssum[1024];
  int tid = threadIdx.x;
  int chunk = (n + 1023) / 1024;
  int b = tid * chunk;
  int e = min(n, b + chunk);
  int s = 0;
  for (int i = b; i < e; ++i) s += cnt[i];
  ssum[tid] = s;
  __syncthreads();
  for (int off = 1; off < 1024; off <<= 1) {
    int v = (tid >= off) ? ssum[tid - off] : 0;
    __syncthreads();
    ssum[tid] += v;
    __syncthreads();
  }
  if (tid == 0) rowptr[n] = ssum[1023];
  int pre = (tid == 0) ? 0 : ssum[tid - 1];
  for (int i = b; i < e; ++i) { rowptr[i] = pre; pre += cnt[i]; }
}

// ---------------- CSR fill (by dst) ----------------
__global__ void fill_kernel(const int* __restrict__ src, const int* __restrict__ dst,
                            const float* __restrict__ dinv, const int* __restrict__ rowptr,
                            int* __restrict__ fillc, int* __restrict__ csr_src,
                            float* __restrict__ csr_w, int E) {
  int e = blockIdx.x * blockDim.x + threadIdx.x;
  if (e < E) {
    int s = src[e], d = dst[e];
    int pos = rowptr[d] + atomicAdd(&fillc[d], 1);
    csr_src[pos] = s;
    csr_w[pos] = -dinv[s] * dinv[d];
  }
}

// ---------------- combined-weight prep: G_l = [W0-W2 ; W1 ; 2*W2] ----------------
__global__ void prep_kernel(const float* __restrict__ W1, const float* __restrict__ W2,
                            const float* __restrict__ W3, float* __restrict__ G) {
  const int MS = FDIM * FDIM;
  int i = blockIdx.x * blockDim.x + threadIdx.x;
  if (i < MS) {
    const float* Ws[3] = {W1, W2, W3};
#pragma unroll
    for (int l = 0; l < 3; ++l) {
      const float* W = Ws[l];
      float* g = G + (size_t)l * 3 * MS;
      float w0 = W[i], w1 = W[MS + i], w2 = W[2 * MS + i];
      g[i] = w0 - w2;
      g[MS + i] = w1;
      g[2 * MS + i] = 2.f * w2;
    }
  }
}

// ---------------- propagation: out[i] = sum_{e in row i} w_e * x[src_e] ----------------
// one wave (64 lanes) per dst node; lane = 2 features (float2)
__global__ __launch_bounds__(256) void prop_kernel(
    const float* __restrict__ x, float* __restrict__ out,
    const int* __restrict__ rowptr, const int* __restrict__ csr_src,
    const float* __restrict__ csr_w, int n) {
  int node = (int)(((size_t)blockIdx.x * blockDim.x + threadIdx.x) >> 6);
  int lane = threadIdx.x & 63;
  if (node >= n) return;
  int beg = rowptr[node], end = rowptr[node + 1];
  float2 acc = make_float2(0.f, 0.f);
  for (int base = beg; base < end; base += 64) {
    int m = end - base; if (m > 64) m = 64;
    int s = 0; float w = 0.f;
    if (lane < m) { s = csr_src[base + lane]; w = csr_w[base + lane]; }
    for (int j = 0; j < m; ++j) {
      int sj = __shfl(s, j);
      float wj = __shfl(w, j);
      float2 v = *(const float2*)(x + (size_t)sj * FDIM + lane * 2);
      acc.x = fmaf(wj, v.x, acc.x);
      acc.y = fmaf(wj, v.y, acc.y);
    }
  }
  *(float2*)(out + (size_t)node * FDIM + lane * 2) = acc;
}

// ---------------- fused 3-source GEMM: C = act(A0@G0 + A1@G1 + A2@G2 + b) ----------------
// BM=64 rows x BN=128 cols per block, 128 threads, 8x8 register tile, KC=32 LDS chunks.
#define BM 64
#define BN 128
#define KC 32
__global__ __launch_bounds__(128) void gemm3_kernel(
    const float* __restrict__ A0, const float* __restrict__ A1, const float* __restrict__ A2,
    const float* __restrict__ G, const float* __restrict__ bias,
    float* __restrict__ C, int n, int do_relu) {
  __shared__ float a_s[KC][BM];
  __shared__ float b_s[KC][BN];
  const int tid = threadIdx.x;
  const int bm0 = blockIdx.x * BM;
  const int tn = (tid & 15) * 8;
  const int tm = (tid >> 4) * 8;
  float acc[8][8];
#pragma unroll
  for (int i = 0; i < 8; ++i)
#pragma unroll
    for (int j = 0; j < 8; ++j) acc[i][j] = 0.f;

  const float* Asrc[3] = {A0, A1, A2};
#pragma unroll
  for (int s = 0; s < 3; ++s) {
    const float* A = Asrc[s];
    const float* Bm = G + (size_t)s * FDIM * FDIM;
    for (int k0 = 0; k0 < FDIM; k0 += KC) {
      __syncthreads();
      // stage A chunk transposed: a_s[k][m] = A[bm0+m][k0+k]
      for (int t = tid; t < BM * KC / 4; t += 128) {
        int m = t >> 3;            // 8 float4 per 32-col row chunk
        int kk = (t & 7) * 4;
        int gm = bm0 + m; if (gm >= n) gm = n - 1;
        float4 v = *(const float4*)(A + (size_t)gm * FDIM + k0 + kk);
        a_s[kk + 0][m] = v.x; a_s[kk + 1][m] = v.y;
        a_s[kk + 2][m] = v.z; a_s[kk + 3][m] = v.w;
      }
      // stage B chunk: b_s[k][nn]
      for (int t = tid; t < KC * BN / 4; t += 128) {
        int k = t >> 5;            // 32 float4 per row
        int nn = (t & 31) * 4;
        *(float4*)&b_s[k][nn] = *(const float4*)(Bm + (size_t)(k0 + k) * FDIM + nn);
      }
      __syncthreads();
#pragma unroll
      for (int k = 0; k < KC; ++k) {
        float af[8], bf[8];
        *(float4*)&af[0] = *(const float4*)&a_s[k][tm];
        *(float4*)&af[4] = *(const float4*)&a_s[k][tm + 4];
        *(float4*)&bf[0] = *(const float4*)&b_s[k][tn];
        *(float4*)&bf[4] = *(const float4*)&b_s[k][tn + 4];
#pragma unroll
        for (int i = 0; i < 8; ++i)
#pragma unroll
          for (int j = 0; j < 8; ++j)
            acc[i][j] = fmaf(af[i], bf[j], acc[i][j]);
      }
    }
  }
  float bfr[8];
#pragma unroll
  for (int j = 0; j < 8; ++j) bfr[j] = bias[tn + j];
#pragma unroll
  for (int i = 0; i < 8; ++i) {
    int gm = bm0 + tm + i;
    if (gm < n) {
      float o[8];
#pragma unroll
      for (int j = 0; j < 8; ++j) {
        float v = acc[i][j] + bfr[j];
        o[j] = do_relu ? fmaxf(v, 0.f) : v;
      }
      *(float4*)(C + (size_t)gm * FDIM + tn)     = *(float4*)&o[0];
      *(float4*)(C + (size_t)gm * FDIM + tn + 4) = *(float4*)&o[4];
    }
  }
}

// ---------------- pooling ----------------
__device__ __forceinline__ int lb_search(const int* __restrict__ b, int n, int val) {
  int lo = 0, hi = n;
  while (lo < hi) { int mid = (lo + hi) >> 1; if (b[mid] < val) lo = mid + 1; else hi = mid; }
  return lo;
}

__global__ void pool_kernel(const float* __restrict__ h, const int* __restrict__ batch,
                            float* __restrict__ sums, int* __restrict__ cntg, int n) {
  int g = blockIdx.x, s = blockIdx.y;
  int beg = lb_search(batch, n, g);
  int end = lb_search(batch, n, g + 1);
  if (s == 0 && threadIdx.x == 0) cntg[g] = end - beg;
  long long len = end - beg;
  int c0 = beg + (int)((len * s) / 8);
  int c1 = beg + (int)((len * (s + 1)) / 8);
  int f = threadIdx.x;  // 128 threads
  float acc = 0.f;
  for (int r = c0; r < c1; ++r) acc += h[(size_t)r * FDIM + f];
  if (c1 > c0) atomicAdd(&sums[g * FDIM + f], acc);
}

__global__ void final_kernel(const float* __restrict__ sums, const int* __restrict__ cntg,
                             const float* __restrict__ Wl, const float* __restrict__ bl,
                             float* __restrict__ out) {
  int g = blockIdx.x;
  __shared__ float row[FDIM];
  int t = threadIdx.x;  // 128 threads
  float inv = 1.f / fmaxf((float)cntg[g], 1.f);
  row[t] = sums[g * FDIM + t] * inv;
  __syncthreads();
  if (t < CLSN) {
    float a = bl[t];
#pragma unroll 4
    for (int f = 0; f < FDIM; ++f) a = fmaf(row[f], Wl[f * CLSN + t], a);
    out[g * CLSN + t] = a;
  }
}

// ---------------- launch ----------------
extern "C" void kernel_launch(void* const* d_in, const int* in_sizes, int n_in,
                              void* d_out, int out_size, void* d_ws, size_t ws_size,
                              hipStream_t stream) {
  const float* x   = (const float*)d_in[0];
  const int*   ei  = (const int*)d_in[1];
  const int* batch = (const int*)d_in[2];
  const float* W1  = (const float*)d_in[3];
  const float* b1  = (const float*)d_in[4];
  const float* W2  = (const float*)d_in[5];
  const float* b2  = (const float*)d_in[6];
  const float* W3  = (const float*)d_in[7];
  const float* b3  = (const float*)d_in[8];
  const float* Wl  = (const float*)d_in[9];
  const float* bl  = (const float*)d_in[10];
  float* out = (float*)d_out;

  const int n = in_sizes[0] / FDIM;      // 100000
  const int E = in_sizes[1] / 2;         // 1600000
  const int* esrc = ei;
  const int* edst = ei + E;

  char* ws = (char*)d_ws;
  size_t off = 0;
  auto alloc = [&](size_t bytes) -> void* {
    void* p = ws + off;
    off += (bytes + 255) & ~(size_t)255;
    return p;
  };
  const size_t NB = (size_t)n * FDIM * sizeof(float);
  float* B0      = (float*)alloc(NB);
  float* B1      = (float*)alloc(NB);
  float* B2      = (float*)alloc(NB);
  int*   csr_src = (int*)alloc((size_t)E * 4);
  float* csr_w   = (float*)alloc((size_t)E * 4);
  int*   rowptr  = (int*)alloc(((size_t)n + 1) * 4);
  float* dinv    = (float*)alloc((size_t)n * 4);
  float* G       = (float*)alloc((size_t)3 * 3 * FDIM * FDIM * 4);
  // zeroed region (one memset): deg | cnt | fillc | sums | cntg
  char*  zbase   = ws + off;
  int*   deg     = (int*)alloc((size_t)n * 4);
  int*   cnt     = (int*)alloc((size_t)n * 4);
  int*   fillc   = (int*)alloc((size_t)n * 4);
  float* sums    = (float*)alloc((size_t)64 * FDIM * 4);
  int*   cntg    = (int*)alloc((size_t)64 * 4);
  size_t zsize   = (size_t)((ws + off) - zbase);
  hipMemsetAsync(zbase, 0, zsize, stream);

  const int MS3 = 3 * FDIM * FDIM;

  prep_kernel<<<(FDIM * FDIM + 255) / 256, 256, 0, stream>>>(W1, W2, W3, G);
  deg_cnt_kernel<<<(E + 255) / 256, 256, 0, stream>>>(esrc, edst, deg, cnt, E);
  dinv_kernel<<<(n + 255) / 256, 256, 0, stream>>>(deg, dinv, n);
  scan_kernel<<<1, 1024, 0, stream>>>(cnt, rowptr, n);
  fill_kernel<<<(E + 255) / 256, 256, 0, stream>>>(esrc, edst, dinv, rowptr, fillc,
                                                   csr_src, csr_w, E);

  int prop_grid = (n + 3) / 4;          // 4 nodes (waves) per 256-thread block
  int gemm_grid = (n + BM - 1) / BM;

  // layer 1: T0=x, T1=B0, P1=B1 -> H=B2 (relu)
  prop_kernel<<<prop_grid, 256, 0, stream>>>(x,  B0, rowptr, csr_src, csr_w, n);
  prop_kernel<<<prop_grid, 256, 0, stream>>>(B0, B1, rowptr, csr_src, csr_w, n);
  gemm3_kernel<<<gemm_grid, 128, 0, stream>>>(x, B0, B1, G, b1, B2, n, 1);

  // layer 2: T0=B2 -> H=B2 in-place (safe: each block reads only its own rows)
  prop_kernel<<<prop_grid, 256, 0, stream>>>(B2, B0, rowptr, csr_src, csr_w, n);
  prop_kernel<<<prop_grid, 256, 0, stream>>>(B0, B1, rowptr, csr_src, csr_w, n);
  gemm3_kernel<<<gemm_grid, 128, 0, stream>>>(B2, B0, B1, G + MS3, b2, B2, n, 1);

  // layer 3: no relu
  prop_kernel<<<prop_grid, 256, 0, stream>>>(B2, B0, rowptr, csr_src, csr_w, n);
  prop_kernel<<<prop_grid, 256, 0, stream>>>(B0, B1, rowptr, csr_src, csr_w, n);
  gemm3_kernel<<<gemm_grid, 128, 0, stream>>>(B2, B0, B1, G + 2 * MS3, b3, B2, n, 0);

  // pool + classifier
  pool_kernel<<<dim3(64, 8), 128, 0, stream>>>(B2, batch, sums, cntg, n);
  final_kernel<<<64, 128, 0, stream>>>(sums, cntg, Wl, bl, out);
}

// Round 2
// 1405.558 us; speedup vs baseline: 1.5573x; 1.5573x over previous
//
#include <hip/hip_runtime.h>
#include <cstdint>
#include <cstddef>

#define FDIM 128
#define CLSN 10

typedef __attribute__((ext_vector_type(8))) short short8;
typedef __attribute__((ext_vector_type(4))) float f32x4;

__device__ __forceinline__ unsigned short f2bf_hi(float f) {
  unsigned u = __float_as_uint(f);
  unsigned r = (u + 0x7FFFu + ((u >> 16) & 1u)) >> 16;
  return (unsigned short)r;
}
__device__ __forceinline__ float bf2f(unsigned short h) {
  return __uint_as_float(((unsigned)h) << 16);
}

// ---------------- degree / count ----------------
__global__ void deg_cnt_kernel(const int* __restrict__ src, const int* __restrict__ dst,
                               int* __restrict__ deg, int* __restrict__ cnt, int E) {
  int e = blockIdx.x * blockDim.x + threadIdx.x;
  if (e < E) {
    atomicAdd(&deg[src[e]], 1);
    atomicAdd(&cnt[dst[e]], 1);
  }
}

__global__ void dinv_kernel(const int* __restrict__ deg, float* __restrict__ dinv, int n) {
  int i = blockIdx.x * blockDim.x + threadIdx.x;
  if (i < n) {
    int d = deg[i];
    dinv[i] = d > 0 ? rsqrtf((float)d) : 0.0f;
  }
}

// ---------------- exclusive scan (single block, 1024 threads) ----------------
__global__ void scan_kernel(const int* __restrict__ cnt, int* __restrict__ rowptr, int n) {
  __shared__ int ssum[1024];
  int tid = threadIdx.x;
  int chunk = (n + 1023) / 1024;
  int b = tid * chunk;
  int e = min(n, b + chunk);
  int s = 0;
  for (int i = b; i < e; ++i) s += cnt[i];
  ssum[tid] = s;
  __syncthreads();
  for (int off = 1; off < 1024; off <<= 1) {
    int v = (tid >= off) ? ssum[tid - off] : 0;
    __syncthreads();
    ssum[tid] += v;
    __syncthreads();
  }
  if (tid == 0) rowptr[n] = ssum[1023];
  int pre = (tid == 0) ? 0 : ssum[tid - 1];
  for (int i = b; i < e; ++i) { rowptr[i] = pre; pre += cnt[i]; }
}

// ---------------- CSR fill (by dst), interleaved (src, w) ----------------
__global__ void fill_kernel(const int* __restrict__ src, const int* __restrict__ dst,
                            const float* __restrict__ dinv, const int* __restrict__ rowptr,
                            int* __restrict__ fillc, int2* __restrict__ csr_ew, int E) {
  int e = blockIdx.x * blockDim.x + threadIdx.x;
  if (e < E) {
    int s = src[e], d = dst[e];
    int pos = rowptr[d] + atomicAdd(&fillc[d], 1);
    float w = -dinv[s] * dinv[d];
    csr_ew[pos] = make_int2(s, __float_as_int(w));
  }
}

// ---------------- weight prep: combine, split hi/lo, swizzle to B-fragment order ----
// Layout: idx = ((((L*3+S)*4 + c)*8 + t)*64 + lane)*8 + j
//   where k = c*32 + (lane>>4)*8 + j, col = t*16 + (lane&15)
__global__ void prep_kernel(const float* __restrict__ W1, const float* __restrict__ W2,
                            const float* __restrict__ W3,
                            unsigned short* __restrict__ Gh, unsigned short* __restrict__ Gl) {
  const int MS = FDIM * FDIM;
  int idx = blockIdx.x * blockDim.x + threadIdx.x;
  if (idx >= 3 * 3 * MS) return;
  int L = idx / (3 * MS);
  int rem = idx - L * 3 * MS;
  int S = rem / MS;
  int e = rem - S * MS;            // e = k*128 + nn
  int k = e >> 7, nn = e & 127;
  const float* W = (L == 0) ? W1 : (L == 1) ? W2 : W3;
  float w0 = W[e], w1 = W[MS + e], w2 = W[2 * MS + e];
  float v = (S == 0) ? (w0 - w2) : (S == 1) ? w1 : (2.f * w2);
  unsigned short hi = f2bf_hi(v);
  unsigned short lo = f2bf_hi(v - bf2f(hi));
  int c = k >> 5, q = (k >> 3) & 3, j = k & 7;
  int t = nn >> 4, nl = nn & 15;
  int lane = q * 16 + nl;
  size_t out = ((((size_t)(L * 3 + S) * 4 + c) * 8 + t) * 64 + lane) * 8 + j;
  Gh[out] = hi;
  Gl[out] = lo;
}

// ---------------- propagation: out[i] = sum_{e in row i} w_e * x[src_e] ----------------
// one wave (64 lanes) per dst node; lane = 2 features (float2)
__global__ __launch_bounds__(256) void prop_kernel(
    const float* __restrict__ x, float* __restrict__ out,
    const int* __restrict__ rowptr, const int2* __restrict__ csr_ew, int n) {
  int node = (int)(((size_t)blockIdx.x * blockDim.x + threadIdx.x) >> 6);
  int lane = threadIdx.x & 63;
  if (node >= n) return;
  int beg = rowptr[node], end = rowptr[node + 1];
  float2 acc0 = make_float2(0.f, 0.f);
  float2 acc1 = make_float2(0.f, 0.f);
  for (int base = beg; base < end; base += 64) {
    int m = end - base; if (m > 64) m = 64;
    int s = 0; float w = 0.f;
    if (lane < m) { int2 sw = csr_ew[base + lane]; s = sw.x; w = __int_as_float(sw.y); }
    int j = 0;
    for (; j + 1 < m; j += 2) {
      int s0 = __shfl(s, j);
      int s1 = __shfl(s, j + 1);
      float w0 = __shfl(w, j);
      float w1 = __shfl(w, j + 1);
      float2 v0 = *(const float2*)(x + (size_t)s0 * FDIM + lane * 2);
      float2 v1 = *(const float2*)(x + (size_t)s1 * FDIM + lane * 2);
      acc0.x = fmaf(w0, v0.x, acc0.x);
      acc0.y = fmaf(w0, v0.y, acc0.y);
      acc1.x = fmaf(w1, v1.x, acc1.x);
      acc1.y = fmaf(w1, v1.y, acc1.y);
    }
    if (j < m) {
      int s0 = __shfl(s, j);
      float w0 = __shfl(w, j);
      float2 v0 = *(const float2*)(x + (size_t)s0 * FDIM + lane * 2);
      acc0.x = fmaf(w0, v0.x, acc0.x);
      acc0.y = fmaf(w0, v0.y, acc0.y);
    }
  }
  float2 r = make_float2(acc0.x + acc1.x, acc0.y + acc1.y);
  *(float2*)(out + (size_t)node * FDIM + lane * 2) = r;
}

// ---------------- split-bf16 MFMA GEMM: C = act([A0|A1|A2] @ [G0;G1;G2] + b) ----------
// Block: 256 threads (4 waves, 2x2), tile 128 rows x 128 cols.
// Each wave: 64x64 via 4x4 grid of 16x16x32 MFMA tiles. K chunks of 32.
#define GBM 128
#define APAD 40  // LDS row stride in bf16 elems (80 B, 16B-aligned, 2-way conflicts only)
__global__ __launch_bounds__(256) void gemm3_mfma_kernel(
    const float* __restrict__ A0, const float* __restrict__ A1, const float* __restrict__ A2,
    const unsigned short* __restrict__ Gh, const unsigned short* __restrict__ Gl,
    const float* __restrict__ bias, float* __restrict__ C, int n, int layer, int do_relu) {
  __shared__ unsigned short ah_s[GBM * APAD];
  __shared__ unsigned short al_s[GBM * APAD];
  const int tid = threadIdx.x;
  const int lane = tid & 63;
  const int wave = tid >> 6;
  const int wm = wave >> 1, wn = wave & 1;
  const int bm0 = blockIdx.x * GBM;
  const int lm = lane & 15, lq = lane >> 4;

  f32x4 acc[4][4];
#pragma unroll
  for (int mt = 0; mt < 4; ++mt)
#pragma unroll
    for (int nt = 0; nt < 4; ++nt) acc[mt][nt] = (f32x4){0.f, 0.f, 0.f, 0.f};

  const float* Asrc[3] = {A0, A1, A2};
#pragma unroll 1
  for (int S = 0; S < 3; ++S) {
    const float* A = Asrc[S];
#pragma unroll 1
    for (int c = 0; c < 4; ++c) {
      __syncthreads();
      // stage 128 rows x 32 k of fp32 A -> bf16 hi/lo planes in LDS
#pragma unroll
      for (int i = 0; i < 4; ++i) {
        int id = tid + i * 256;
        int row = id >> 3, cg = (id & 7) * 4;
        int gr = bm0 + row; if (gr >= n) gr = n - 1;
        float4 v = *(const float4*)(A + (size_t)gr * FDIM + c * 32 + cg);
        unsigned short h0 = f2bf_hi(v.x), h1 = f2bf_hi(v.y), h2 = f2bf_hi(v.z), h3 = f2bf_hi(v.w);
        unsigned short l0 = f2bf_hi(v.x - bf2f(h0)), l1 = f2bf_hi(v.y - bf2f(h1));
        unsigned short l2 = f2bf_hi(v.z - bf2f(h2)), l3 = f2bf_hi(v.w - bf2f(h3));
        unsigned long long hp = (unsigned long long)h0 | ((unsigned long long)h1 << 16) |
                                ((unsigned long long)h2 << 32) | ((unsigned long long)h3 << 48);
        unsigned long long lp = (unsigned long long)l0 | ((unsigned long long)l1 << 16) |
                                ((unsigned long long)l2 << 32) | ((unsigned long long)l3 << 48);
        *(unsigned long long*)&ah_s[row * APAD + cg] = hp;
        *(unsigned long long*)&al_s[row * APAD + cg] = lp;
      }
      __syncthreads();
      // A fragments from LDS
      short8 ah[4], al[4];
#pragma unroll
      for (int mt = 0; mt < 4; ++mt) {
        int r = wm * 64 + mt * 16 + lm;
        ah[mt] = *(const short8*)&ah_s[r * APAD + lq * 8];
        al[mt] = *(const short8*)&al_s[r * APAD + lq * 8];
      }
      // B fragments direct from swizzled global (L2-resident)
      short8 bh[4], bl[4];
      size_t gb = (((size_t)(layer * 3 + S) * 4 + c) * 8) * 512;
#pragma unroll
      for (int nt = 0; nt < 4; ++nt) {
        int t = wn * 4 + nt;
        size_t o = gb + ((size_t)t * 64 + lane) * 8;
        bh[nt] = *(const short8*)(Gh + o);
        bl[nt] = *(const short8*)(Gl + o);
      }
#pragma unroll
      for (int mt = 0; mt < 4; ++mt)
#pragma unroll
        for (int nt = 0; nt < 4; ++nt) {
          acc[mt][nt] = __builtin_amdgcn_mfma_f32_16x16x32_bf16(ah[mt], bh[nt], acc[mt][nt], 0, 0, 0);
          acc[mt][nt] = __builtin_amdgcn_mfma_f32_16x16x32_bf16(ah[mt], bl[nt], acc[mt][nt], 0, 0, 0);
          acc[mt][nt] = __builtin_amdgcn_mfma_f32_16x16x32_bf16(al[mt], bh[nt], acc[mt][nt], 0, 0, 0);
        }
    }
  }
  // epilogue: C/D layout col=lane&15, row=(lane>>4)*4+reg
  float bv[4];
#pragma unroll
  for (int nt = 0; nt < 4; ++nt) bv[nt] = bias[wn * 64 + nt * 16 + lm];
#pragma unroll
  for (int mt = 0; mt < 4; ++mt) {
#pragma unroll
    for (int r = 0; r < 4; ++r) {
      int row = bm0 + wm * 64 + mt * 16 + lq * 4 + r;
      if (row < n) {
#pragma unroll
        for (int nt = 0; nt < 4; ++nt) {
          float v = acc[mt][nt][r] + bv[nt];
          if (do_relu) v = fmaxf(v, 0.f);
          C[(size_t)row * FDIM + wn * 64 + nt * 16 + lm] = v;
        }
      }
    }
  }
}

// ---------------- pooling ----------------
__device__ __forceinline__ int lb_search(const int* __restrict__ b, int n, int val) {
  int lo = 0, hi = n;
  while (lo < hi) { int mid = (lo + hi) >> 1; if (b[mid] < val) lo = mid + 1; else hi = mid; }
  return lo;
}

__global__ void pool_kernel(const float* __restrict__ h, const int* __restrict__ batch,
                            float* __restrict__ sums, int* __restrict__ cntg, int n) {
  int g = blockIdx.x, s = blockIdx.y;
  int beg = lb_search(batch, n, g);
  int end = lb_search(batch, n, g + 1);
  if (s == 0 && threadIdx.x == 0) cntg[g] = end - beg;
  long long len = end - beg;
  int c0 = beg + (int)((len * s) / 8);
  int c1 = beg + (int)((len * (s + 1)) / 8);
  int f = threadIdx.x;  // 128 threads
  float acc = 0.f;
  for (int r = c0; r < c1; ++r) acc += h[(size_t)r * FDIM + f];
  if (c1 > c0) atomicAdd(&sums[g * FDIM + f], acc);
}

__global__ void final_kernel(const float* __restrict__ sums, const int* __restrict__ cntg,
                             const float* __restrict__ Wl, const float* __restrict__ bl,
                             float* __restrict__ out) {
  int g = blockIdx.x;
  __shared__ float row[FDIM];
  int t = threadIdx.x;  // 128 threads
  float inv = 1.f / fmaxf((float)cntg[g], 1.f);
  row[t] = sums[g * FDIM + t] * inv;
  __syncthreads();
  if (t < CLSN) {
    float a = bl[t];
#pragma unroll 4
    for (int f = 0; f < FDIM; ++f) a = fmaf(row[f], Wl[f * CLSN + t], a);
    out[g * CLSN + t] = a;
  }
}

// ---------------- launch ----------------
extern "C" void kernel_launch(void* const* d_in, const int* in_sizes, int n_in,
                              void* d_out, int out_size, void* d_ws, size_t ws_size,
                              hipStream_t stream) {
  const float* x   = (const float*)d_in[0];
  const int*   ei  = (const int*)d_in[1];
  const int* batch = (const int*)d_in[2];
  const float* W1  = (const float*)d_in[3];
  const float* b1  = (const float*)d_in[4];
  const float* W2  = (const float*)d_in[5];
  const float* b2  = (const float*)d_in[6];
  const float* W3  = (const float*)d_in[7];
  const float* b3  = (const float*)d_in[8];
  const float* Wl  = (const float*)d_in[9];
  const float* bl  = (const float*)d_in[10];
  float* out = (float*)d_out;

  const int n = in_sizes[0] / FDIM;      // 100000
  const int E = in_sizes[1] / 2;         // 1600000
  const int* esrc = ei;
  const int* edst = ei + E;

  char* ws = (char*)d_ws;
  size_t off = 0;
  auto alloc = [&](size_t bytes) -> void* {
    void* p = ws + off;
    off += (bytes + 255) & ~(size_t)255;
    return p;
  };
  const size_t NB = (size_t)n * FDIM * sizeof(float);
  float* B0      = (float*)alloc(NB);
  float* B1      = (float*)alloc(NB);
  float* B2      = (float*)alloc(NB);
  int2*  csr_ew  = (int2*)alloc((size_t)E * 8);
  int*   rowptr  = (int*)alloc(((size_t)n + 1) * 4);
  float* dinv    = (float*)alloc((size_t)n * 4);
  unsigned short* Gh = (unsigned short*)alloc((size_t)3 * 3 * FDIM * FDIM * 2);
  unsigned short* Gl = (unsigned short*)alloc((size_t)3 * 3 * FDIM * FDIM * 2);
  // zeroed region (one memset): deg | cnt | fillc | sums | cntg
  char*  zbase   = ws + off;
  int*   deg     = (int*)alloc((size_t)n * 4);
  int*   cnt     = (int*)alloc((size_t)n * 4);
  int*   fillc   = (int*)alloc((size_t)n * 4);
  float* sums    = (float*)alloc((size_t)64 * FDIM * 4);
  int*   cntg    = (int*)alloc((size_t)64 * 4);
  size_t zsize   = (size_t)((ws + off) - zbase);
  hipMemsetAsync(zbase, 0, zsize, stream);

  prep_kernel<<<(3 * 3 * FDIM * FDIM + 255) / 256, 256, 0, stream>>>(W1, W2, W3, Gh, Gl);
  deg_cnt_kernel<<<(E + 255) / 256, 256, 0, stream>>>(esrc, edst, deg, cnt, E);
  dinv_kernel<<<(n + 255) / 256, 256, 0, stream>>>(deg, dinv, n);
  scan_kernel<<<1, 1024, 0, stream>>>(cnt, rowptr, n);
  fill_kernel<<<(E + 255) / 256, 256, 0, stream>>>(esrc, edst, dinv, rowptr, fillc,
                                                   csr_ew, E);

  int prop_grid = (n + 3) / 4;               // 4 nodes (waves) per 256-thread block
  int gemm_grid = (n + GBM - 1) / GBM;       // 782

  // layer 1
  prop_kernel<<<prop_grid, 256, 0, stream>>>(x,  B0, rowptr, csr_ew, n);
  prop_kernel<<<prop_grid, 256, 0, stream>>>(B0, B1, rowptr, csr_ew, n);
  gemm3_mfma_kernel<<<gemm_grid, 256, 0, stream>>>(x, B0, B1, Gh, Gl, b1, B2, n, 0, 1);

  // layer 2 (in-place on B2 is safe: block reads only its own rows)
  prop_kernel<<<prop_grid, 256, 0, stream>>>(B2, B0, rowptr, csr_ew, n);
  prop_kernel<<<prop_grid, 256, 0, stream>>>(B0, B1, rowptr, csr_ew, n);
  gemm3_mfma_kernel<<<gemm_grid, 256, 0, stream>>>(B2, B0, B1, Gh, Gl, b2, B2, n, 1, 1);

  // layer 3: no relu
  prop_kernel<<<prop_grid, 256, 0, stream>>>(B2, B0, rowptr, csr_ew, n);
  prop_kernel<<<prop_grid, 256, 0, stream>>>(B0, B1, rowptr, csr_ew, n);
  gemm3_mfma_kernel<<<gemm_grid, 256, 0, stream>>>(B2, B0, B1, Gh, Gl, b3, B2, n, 2, 0);

  // pool + classifier
  pool_kernel<<<dim3(64, 8), 128, 0, stream>>>(B2, batch, sums, cntg, n);
  final_kernel<<<64, 128, 0, stream>>>(sums, cntg, Wl, bl, out);
}

// Round 3
// 1272.070 us; speedup vs baseline: 1.7207x; 1.1049x over previous
//
#include <hip/hip_runtime.h>
#include <cstdint>
#include <cstddef>

#define FDIM 128
#define CLSN 10

typedef __attribute__((ext_vector_type(8))) short short8;
typedef __attribute__((ext_vector_type(4))) float f32x4;

__device__ __forceinline__ unsigned short f2bf_hi(float f) {
  unsigned u = __float_as_uint(f);
  unsigned r = (u + 0x7FFFu + ((u >> 16) & 1u)) >> 16;
  return (unsigned short)r;
}
__device__ __forceinline__ float bf2f(unsigned short h) {
  return __uint_as_float(((unsigned)h) << 16);
}

// ---------------- degree / count ----------------
__global__ void deg_cnt_kernel(const int* __restrict__ src, const int* __restrict__ dst,
                               int* __restrict__ deg, int* __restrict__ cnt, int E) {
  int e = blockIdx.x * blockDim.x + threadIdx.x;
  if (e < E) {
    atomicAdd(&deg[src[e]], 1);
    atomicAdd(&cnt[dst[e]], 1);
  }
}

__global__ void dinv_kernel(const int* __restrict__ deg, float* __restrict__ dinv, int n) {
  int i = blockIdx.x * blockDim.x + threadIdx.x;
  if (i < n) {
    int d = deg[i];
    dinv[i] = d > 0 ? rsqrtf((float)d) : 0.0f;
  }
}

// ---------------- 3-phase parallel exclusive scan ----------------
#define SCB 1024
__global__ __launch_bounds__(SCB) void scan1_kernel(const int* __restrict__ cnt,
                                                    int* __restrict__ rowptr,
                                                    int* __restrict__ btot, int n) {
  __shared__ int sh[SCB];
  int tid = threadIdx.x;
  int i = blockIdx.x * SCB + tid;
  int v = (i < n) ? cnt[i] : 0;
  sh[tid] = v;
  __syncthreads();
  for (int off = 1; off < SCB; off <<= 1) {
    int t = (tid >= off) ? sh[tid - off] : 0;
    __syncthreads();
    sh[tid] += t;
    __syncthreads();
  }
  if (i < n) rowptr[i] = sh[tid] - v;   // exclusive
  if (tid == SCB - 1) btot[blockIdx.x] = sh[tid];
}

__global__ __launch_bounds__(1024) void scan2_kernel(const int* __restrict__ btot,
                                                     int* __restrict__ boff,
                                                     int* __restrict__ total_out, int nb) {
  __shared__ int sh[1024];
  int tid = threadIdx.x;
  int v = (tid < nb) ? btot[tid] : 0;
  sh[tid] = v;
  __syncthreads();
  for (int off = 1; off < 1024; off <<= 1) {
    int t = (tid >= off) ? sh[tid - off] : 0;
    __syncthreads();
    sh[tid] += t;
    __syncthreads();
  }
  if (tid < nb) boff[tid] = sh[tid] - v;
  if (tid == 1023) *total_out = sh[tid];
}

__global__ __launch_bounds__(SCB) void scan3_kernel(int* __restrict__ rowptr,
                                                    const int* __restrict__ boff, int n) {
  int i = blockIdx.x * SCB + threadIdx.x;
  if (i < n) rowptr[i] += boff[blockIdx.x];
}

// ---------------- CSR fill (by dst), interleaved (src, w) ----------------
__global__ void fill_kernel(const int* __restrict__ src, const int* __restrict__ dst,
                            const float* __restrict__ dinv, const int* __restrict__ rowptr,
                            int* __restrict__ fillc, int2* __restrict__ csr_ew, int E) {
  int e = blockIdx.x * blockDim.x + threadIdx.x;
  if (e < E) {
    int s = src[e], d = dst[e];
    int pos = rowptr[d] + atomicAdd(&fillc[d], 1);
    float w = -dinv[s] * dinv[d];
    csr_ew[pos] = make_int2(s, __float_as_int(w));
  }
}

// ---------------- weight prep: combine, split hi/lo, swizzle to B-fragment order ----
__global__ void prep_kernel(const float* __restrict__ W1, const float* __restrict__ W2,
                            const float* __restrict__ W3,
                            unsigned short* __restrict__ Gh, unsigned short* __restrict__ Gl) {
  const int MS = FDIM * FDIM;
  int idx = blockIdx.x * blockDim.x + threadIdx.x;
  if (idx >= 3 * 3 * MS) return;
  int L = idx / (3 * MS);
  int rem = idx - L * 3 * MS;
  int S = rem / MS;
  int e = rem - S * MS;            // e = k*128 + nn
  int k = e >> 7, nn = e & 127;
  const float* W = (L == 0) ? W1 : (L == 1) ? W2 : W3;
  float w0 = W[e], w1 = W[MS + e], w2 = W[2 * MS + e];
  float v = (S == 0) ? (w0 - w2) : (S == 1) ? w1 : (2.f * w2);
  unsigned short hi = f2bf_hi(v);
  unsigned short lo = f2bf_hi(v - bf2f(hi));
  int c = k >> 5, q = (k >> 3) & 3, j = k & 7;
  int t = nn >> 4, nl = nn & 15;
  int lane = q * 16 + nl;
  size_t out = ((((size_t)(L * 3 + S) * 4 + c) * 8 + t) * 64 + lane) * 8 + j;
  Gh[out] = hi;
  Gl[out] = lo;
}

// ---------------- propagation: out[i] = sum_{e in row i} w_e * x[src_e] ----------------
// one wave per dst node; 32 lanes = feature (float4), 2 edge-groups, edge unroll x4
// -> up to 8 edges / 4 x 16B loads in flight per wave.
__global__ __launch_bounds__(256) void prop_kernel(
    const float* __restrict__ x, float* __restrict__ out,
    const int* __restrict__ rowptr, const int2* __restrict__ csr_ew, int n) {
  int node = (int)(((size_t)blockIdx.x * blockDim.x + threadIdx.x) >> 6);
  int lane = threadIdx.x & 63;
  if (node >= n) return;
  const int g = lane >> 5, fl = lane & 31;
  int beg = rowptr[node], end = rowptr[node + 1];
  f32x4 a0 = {0.f, 0.f, 0.f, 0.f}, a1 = a0, a2 = a0, a3 = a0;
  const float* xf = x + fl * 4;
  for (int base = beg; base < end; base += 64) {
    int m = end - base; if (m > 64) m = 64;
    int s = 0; float w = 0.f;
    if (lane < m) { int2 sw = csr_ew[base + lane]; s = sw.x; w = __int_as_float(sw.y); }
    int j = 0;
    for (; j + 8 <= m; j += 8) {
      int s0 = __shfl(s, j + g),     s1 = __shfl(s, j + 2 + g);
      int s2 = __shfl(s, j + 4 + g), s3 = __shfl(s, j + 6 + g);
      float w0 = __shfl(w, j + g),     w1 = __shfl(w, j + 2 + g);
      float w2 = __shfl(w, j + 4 + g), w3 = __shfl(w, j + 6 + g);
      f32x4 v0 = *(const f32x4*)(xf + (size_t)s0 * FDIM);
      f32x4 v1 = *(const f32x4*)(xf + (size_t)s1 * FDIM);
      f32x4 v2 = *(const f32x4*)(xf + (size_t)s2 * FDIM);
      f32x4 v3 = *(const f32x4*)(xf + (size_t)s3 * FDIM);
      a0 += w0 * v0; a1 += w1 * v1; a2 += w2 * v2; a3 += w3 * v3;
    }
    for (; j + 2 <= m; j += 2) {
      int s0 = __shfl(s, j + g);
      float w0 = __shfl(w, j + g);
      f32x4 v0 = *(const f32x4*)(xf + (size_t)s0 * FDIM);
      a0 += w0 * v0;
    }
    if (j < m) {
      int s0 = __shfl(s, j);
      float w0 = __shfl(w, j);
      if (g == 0) {
        f32x4 v0 = *(const f32x4*)(xf + (size_t)s0 * FDIM);
        a0 += w0 * v0;
      }
    }
  }
  f32x4 acc = (a0 + a1) + (a2 + a3);
  f32x4 o;
  o.x = __shfl_xor(acc.x, 32);
  o.y = __shfl_xor(acc.y, 32);
  o.z = __shfl_xor(acc.z, 32);
  o.w = __shfl_xor(acc.w, 32);
  acc += o;
  if (g == 0) *(f32x4*)(out + (size_t)node * FDIM + fl * 4) = acc;
}

// ---------------- split-bf16 MFMA GEMM: C = act([A0|A1|A2] @ [G0;G1;G2] + b) ----------
#define GBM 128
#define APAD 40  // LDS row stride in bf16 elems (80 B, 16B-aligned, 2-way conflicts only)
__global__ __launch_bounds__(256) void gemm3_mfma_kernel(
    const float* __restrict__ A0, const float* __restrict__ A1, const float* __restrict__ A2,
    const unsigned short* __restrict__ Gh, const unsigned short* __restrict__ Gl,
    const float* __restrict__ bias, float* __restrict__ C, int n, int layer, int do_relu) {
  __shared__ unsigned short ah_s[GBM * APAD];
  __shared__ unsigned short al_s[GBM * APAD];
  const int tid = threadIdx.x;
  const int lane = tid & 63;
  const int wave = tid >> 6;
  const int wm = wave >> 1, wn = wave & 1;
  const int bm0 = blockIdx.x * GBM;
  const int lm = lane & 15, lq = lane >> 4;

  f32x4 acc[4][4];
#pragma unroll
  for (int mt = 0; mt < 4; ++mt)
#pragma unroll
    for (int nt = 0; nt < 4; ++nt) acc[mt][nt] = (f32x4){0.f, 0.f, 0.f, 0.f};

  const float* Asrc[3] = {A0, A1, A2};
#pragma unroll 1
  for (int S = 0; S < 3; ++S) {
    const float* A = Asrc[S];
#pragma unroll 1
    for (int c = 0; c < 4; ++c) {
      __syncthreads();
#pragma unroll
      for (int i = 0; i < 4; ++i) {
        int id = tid + i * 256;
        int row = id >> 3, cg = (id & 7) * 4;
        int gr = bm0 + row; if (gr >= n) gr = n - 1;
        float4 v = *(const float4*)(A + (size_t)gr * FDIM + c * 32 + cg);
        unsigned short h0 = f2bf_hi(v.x), h1 = f2bf_hi(v.y), h2 = f2bf_hi(v.z), h3 = f2bf_hi(v.w);
        unsigned short l0 = f2bf_hi(v.x - bf2f(h0)), l1 = f2bf_hi(v.y - bf2f(h1));
        unsigned short l2 = f2bf_hi(v.z - bf2f(h2)), l3 = f2bf_hi(v.w - bf2f(h3));
        unsigned long long hp = (unsigned long long)h0 | ((unsigned long long)h1 << 16) |
                                ((unsigned long long)h2 << 32) | ((unsigned long long)h3 << 48);
        unsigned long long lp = (unsigned long long)l0 | ((unsigned long long)l1 << 16) |
                                ((unsigned long long)l2 << 32) | ((unsigned long long)l3 << 48);
        *(unsigned long long*)&ah_s[row * APAD + cg] = hp;
        *(unsigned long long*)&al_s[row * APAD + cg] = lp;
      }
      __syncthreads();
      short8 ah[4], al[4];
#pragma unroll
      for (int mt = 0; mt < 4; ++mt) {
        int r = wm * 64 + mt * 16 + lm;
        ah[mt] = *(const short8*)&ah_s[r * APAD + lq * 8];
        al[mt] = *(const short8*)&al_s[r * APAD + lq * 8];
      }
      short8 bh[4], bl[4];
      size_t gb = (((size_t)(layer * 3 + S) * 4 + c) * 8) * 512;
#pragma unroll
      for (int nt = 0; nt < 4; ++nt) {
        int t = wn * 4 + nt;
        size_t o = gb + ((size_t)t * 64 + lane) * 8;
        bh[nt] = *(const short8*)(Gh + o);
        bl[nt] = *(const short8*)(Gl + o);
      }
#pragma unroll
      for (int mt = 0; mt < 4; ++mt)
#pragma unroll
        for (int nt = 0; nt < 4; ++nt) {
          acc[mt][nt] = __builtin_amdgcn_mfma_f32_16x16x32_bf16(ah[mt], bh[nt], acc[mt][nt], 0, 0, 0);
          acc[mt][nt] = __builtin_amdgcn_mfma_f32_16x16x32_bf16(ah[mt], bl[nt], acc[mt][nt], 0, 0, 0);
          acc[mt][nt] = __builtin_amdgcn_mfma_f32_16x16x32_bf16(al[mt], bh[nt], acc[mt][nt], 0, 0, 0);
        }
    }
  }
  float bv[4];
#pragma unroll
  for (int nt = 0; nt < 4; ++nt) bv[nt] = bias[wn * 64 + nt * 16 + lm];
#pragma unroll
  for (int mt = 0; mt < 4; ++mt) {
#pragma unroll
    for (int r = 0; r < 4; ++r) {
      int row = bm0 + wm * 64 + mt * 16 + lq * 4 + r;
      if (row < n) {
#pragma unroll
        for (int nt = 0; nt < 4; ++nt) {
          float v = acc[mt][nt][r] + bv[nt];
          if (do_relu) v = fmaxf(v, 0.f);
          C[(size_t)row * FDIM + wn * 64 + nt * 16 + lm] = v;
        }
      }
    }
  }
}

// ---------------- pooling ----------------
__device__ __forceinline__ int lb_search(const int* __restrict__ b, int n, int val) {
  int lo = 0, hi = n;
  while (lo < hi) { int mid = (lo + hi) >> 1; if (b[mid] < val) lo = mid + 1; else hi = mid; }
  return lo;
}

__global__ void pool_kernel(const float* __restrict__ h, const int* __restrict__ batch,
                            float* __restrict__ sums, int* __restrict__ cntg, int n) {
  int g = blockIdx.x, s = blockIdx.y;
  int beg = lb_search(batch, n, g);
  int end = lb_search(batch, n, g + 1);
  if (s == 0 && threadIdx.x == 0) cntg[g] = end - beg;
  long long len = end - beg;
  int c0 = beg + (int)((len * s) / 8);
  int c1 = beg + (int)((len * (s + 1)) / 8);
  int f = threadIdx.x;  // 128 threads
  float acc = 0.f;
  for (int r = c0; r < c1; ++r) acc += h[(size_t)r * FDIM + f];
  if (c1 > c0) atomicAdd(&sums[g * FDIM + f], acc);
}

__global__ void final_kernel(const float* __restrict__ sums, const int* __restrict__ cntg,
                             const float* __restrict__ Wl, const float* __restrict__ bl,
                             float* __restrict__ out) {
  int g = blockIdx.x;
  __shared__ float row[FDIM];
  int t = threadIdx.x;  // 128 threads
  float inv = 1.f / fmaxf((float)cntg[g], 1.f);
  row[t] = sums[g * FDIM + t] * inv;
  __syncthreads();
  if (t < CLSN) {
    float a = bl[t];
#pragma unroll 4
    for (int f = 0; f < FDIM; ++f) a = fmaf(row[f], Wl[f * CLSN + t], a);
    out[g * CLSN + t] = a;
  }
}

// ---------------- launch ----------------
extern "C" void kernel_launch(void* const* d_in, const int* in_sizes, int n_in,
                              void* d_out, int out_size, void* d_ws, size_t ws_size,
                              hipStream_t stream) {
  const float* x   = (const float*)d_in[0];
  const int*   ei  = (const int*)d_in[1];
  const int* batch = (const int*)d_in[2];
  const float* W1  = (const float*)d_in[3];
  const float* b1  = (const float*)d_in[4];
  const float* W2  = (const float*)d_in[5];
  const float* b2  = (const float*)d_in[6];
  const float* W3  = (const float*)d_in[7];
  const float* b3  = (const float*)d_in[8];
  const float* Wl  = (const float*)d_in[9];
  const float* bl  = (const float*)d_in[10];
  float* out = (float*)d_out;

  const int n = in_sizes[0] / FDIM;      // 100000
  const int E = in_sizes[1] / 2;         // 1600000
  const int* esrc = ei;
  const int* edst = ei + E;

  char* ws = (char*)d_ws;
  size_t off = 0;
  auto alloc = [&](size_t bytes) -> void* {
    void* p = ws + off;
    off += (bytes + 255) & ~(size_t)255;
    return p;
  };
  const size_t NB = (size_t)n * FDIM * sizeof(float);
  float* B0      = (float*)alloc(NB);
  float* B1      = (float*)alloc(NB);
  float* B2      = (float*)alloc(NB);
  int2*  csr_ew  = (int2*)alloc((size_t)E * 8);
  int*   rowptr  = (int*)alloc(((size_t)n + 1) * 4);
  float* dinv    = (float*)alloc((size_t)n * 4);
  unsigned short* Gh = (unsigned short*)alloc((size_t)3 * 3 * FDIM * FDIM * 2);
  unsigned short* Gl = (unsigned short*)alloc((size_t)3 * 3 * FDIM * FDIM * 2);
  int*   btot    = (int*)alloc(2048 * 4);
  int*   boff    = (int*)alloc(2048 * 4);
  // zeroed region (one memset): deg | cnt | fillc | sums | cntg
  char*  zbase   = ws + off;
  int*   deg     = (int*)alloc((size_t)n * 4);
  int*   cnt     = (int*)alloc((size_t)n * 4);
  int*   fillc   = (int*)alloc((size_t)n * 4);
  float* sums    = (float*)alloc((size_t)64 * FDIM * 4);
  int*   cntg    = (int*)alloc((size_t)64 * 4);
  size_t zsize   = (size_t)((ws + off) - zbase);
  hipMemsetAsync(zbase, 0, zsize, stream);

  prep_kernel<<<(3 * 3 * FDIM * FDIM + 255) / 256, 256, 0, stream>>>(W1, W2, W3, Gh, Gl);
  deg_cnt_kernel<<<(E + 255) / 256, 256, 0, stream>>>(esrc, edst, deg, cnt, E);
  dinv_kernel<<<(n + 255) / 256, 256, 0, stream>>>(deg, dinv, n);

  int nb = (n + SCB - 1) / SCB;          // 98 blocks
  scan1_kernel<<<nb, SCB, 0, stream>>>(cnt, rowptr, btot, n);
  scan2_kernel<<<1, 1024, 0, stream>>>(btot, boff, rowptr + n, nb);
  scan3_kernel<<<nb, SCB, 0, stream>>>(rowptr, boff, n);

  fill_kernel<<<(E + 255) / 256, 256, 0, stream>>>(esrc, edst, dinv, rowptr, fillc,
                                                   csr_ew, E);

  int prop_grid = (n + 3) / 4;               // 4 nodes (waves) per 256-thread block
  int gemm_grid = (n + GBM - 1) / GBM;       // 782

  // layer 1
  prop_kernel<<<prop_grid, 256, 0, stream>>>(x,  B0, rowptr, csr_ew, n);
  prop_kernel<<<prop_grid, 256, 0, stream>>>(B0, B1, rowptr, csr_ew, n);
  gemm3_mfma_kernel<<<gemm_grid, 256, 0, stream>>>(x, B0, B1, Gh, Gl, b1, B2, n, 0, 1);

  // layer 2 (in-place on B2 is safe: block reads only its own rows)
  prop_kernel<<<prop_grid, 256, 0, stream>>>(B2, B0, rowptr, csr_ew, n);
  prop_kernel<<<prop_grid, 256, 0, stream>>>(B0, B1, rowptr, csr_ew, n);
  gemm3_mfma_kernel<<<gemm_grid, 256, 0, stream>>>(B2, B0, B1, Gh, Gl, b2, B2, n, 1, 1);

  // layer 3: no relu
  prop_kernel<<<prop_grid, 256, 0, stream>>>(B2, B0, rowptr, csr_ew, n);
  prop_kernel<<<prop_grid, 256, 0, stream>>>(B0, B1, rowptr, csr_ew, n);
  gemm3_mfma_kernel<<<gemm_grid, 256, 0, stream>>>(B2, B0, B1, Gh, Gl, b3, B2, n, 2, 0);

  // pool + classifier
  pool_kernel<<<dim3(64, 8), 128, 0, stream>>>(B2, batch, sums, cntg, n);
  final_kernel<<<64, 128, 0, stream>>>(sums, cntg, Wl, bl, out);
}

// Round 4
// 887.502 us; speedup vs baseline: 2.4663x; 1.4333x over previous
//
#include <hip/hip_runtime.h>
#include <cstdint>
#include <cstddef>

#define FDIM 128
#define CLSN 10
#define RCAP 64

typedef __attribute__((ext_vector_type(8))) short short8;
typedef __attribute__((ext_vector_type(4))) float f32x4;
typedef __attribute__((ext_vector_type(4))) _Float16 h16x4;

__device__ __forceinline__ unsigned short f2bf_hi(float f) {
  unsigned u = __float_as_uint(f);
  unsigned r = (u + 0x7FFFu + ((u >> 16) & 1u)) >> 16;
  return (unsigned short)r;
}
__device__ __forceinline__ float bf2f(unsigned short h) {
  return __uint_as_float(((unsigned)h) << 16);
}

// ---------------- out-degree (by src) ----------------
__global__ void deg_kernel(const int* __restrict__ src, int* __restrict__ deg, int E) {
  int e = blockIdx.x * blockDim.x + threadIdx.x;
  if (e < E) atomicAdd(&deg[src[e]], 1);
}

__global__ void dinv_kernel(const int* __restrict__ deg, float* __restrict__ dinv, int n) {
  int i = blockIdx.x * blockDim.x + threadIdx.x;
  if (i < n) {
    int d = deg[i];
    dinv[i] = d > 0 ? rsqrtf((float)d) : 0.0f;
  }
}

// ---------------- padded-CSR fill (by dst) ----------------
__global__ void fill_kernel(const int* __restrict__ src, const int* __restrict__ dst,
                            const float* __restrict__ dinv,
                            int* __restrict__ fillc, int2* __restrict__ rows, int E) {
  int e = blockIdx.x * blockDim.x + threadIdx.x;
  if (e < E) {
    int s = src[e], d = dst[e];
    int pos = atomicAdd(&fillc[d], 1);
    if (pos < RCAP) {
      float w = -dinv[s] * dinv[d];
      rows[(size_t)d * RCAP + pos] = make_int2(s, __float_as_int(w));
    }
  }
}

// ---------------- fp32 -> fp16 convert (vectorized x4) ----------------
__global__ void f2h_kernel(const float* __restrict__ in, _Float16* __restrict__ out, int n4) {
  int i = blockIdx.x * blockDim.x + threadIdx.x;
  if (i < n4) {
    float4 v = *(const float4*)(in + (size_t)i * 4);
    h16x4 h = {(_Float16)v.x, (_Float16)v.y, (_Float16)v.z, (_Float16)v.w};
    *(h16x4*)(out + (size_t)i * 4) = h;
  }
}

// ---------------- weight prep: combine, split hi/lo, swizzle to B-fragment order ----
__global__ void prep_kernel(const float* __restrict__ W1, const float* __restrict__ W2,
                            const float* __restrict__ W3,
                            unsigned short* __restrict__ Gh, unsigned short* __restrict__ Gl) {
  const int MS = FDIM * FDIM;
  int idx = blockIdx.x * blockDim.x + threadIdx.x;
  if (idx >= 3 * 3 * MS) return;
  int L = idx / (3 * MS);
  int rem = idx - L * 3 * MS;
  int S = rem / MS;
  int e = rem - S * MS;            // e = k*128 + nn
  int k = e >> 7, nn = e & 127;
  const float* W = (L == 0) ? W1 : (L == 1) ? W2 : W3;
  float w0 = W[e], w1 = W[MS + e], w2 = W[2 * MS + e];
  float v = (S == 0) ? (w0 - w2) : (S == 1) ? w1 : (2.f * w2);
  unsigned short hi = f2bf_hi(v);
  unsigned short lo = f2bf_hi(v - bf2f(hi));
  int c = k >> 5, q = (k >> 3) & 3, j = k & 7;
  int t = nn >> 4, nl = nn & 15;
  int lane = q * 16 + nl;
  size_t out = ((((size_t)(L * 3 + S) * 4 + c) * 8 + t) * 64 + lane) * 8 + j;
  Gh[out] = hi;
  Gl[out] = lo;
}

// ---------------- propagation (fp16 in / fp16 out, fp32 accumulate) ----------------
// one wave per dst node; 32 lanes = feature (fp16x4 = 8B), 2 edge-groups, unroll x4
__global__ __launch_bounds__(256) void prop_kernel(
    const _Float16* __restrict__ x, _Float16* __restrict__ out,
    const int* __restrict__ rcnt, const int2* __restrict__ rows, int n) {
  int node = (int)(((size_t)blockIdx.x * blockDim.x + threadIdx.x) >> 6);
  int lane = threadIdx.x & 63;
  if (node >= n) return;
  const int g = lane >> 5, fl = lane & 31;
  int m = rcnt[node]; if (m > RCAP) m = RCAP;
  const int2* row = rows + (size_t)node * RCAP;
  f32x4 a0 = {0.f, 0.f, 0.f, 0.f}, a1 = a0, a2 = a0, a3 = a0;
  const _Float16* xf = x + fl * 4;
  int s = 0; float w = 0.f;
  if (lane < m) { int2 sw = row[lane]; s = sw.x; w = __int_as_float(sw.y); }
  int j = 0;
  for (; j + 8 <= m; j += 8) {
    int s0 = __shfl(s, j + g),     s1 = __shfl(s, j + 2 + g);
    int s2 = __shfl(s, j + 4 + g), s3 = __shfl(s, j + 6 + g);
    float w0 = __shfl(w, j + g),     w1 = __shfl(w, j + 2 + g);
    float w2 = __shfl(w, j + 4 + g), w3 = __shfl(w, j + 6 + g);
    h16x4 v0 = *(const h16x4*)(xf + (size_t)s0 * FDIM);
    h16x4 v1 = *(const h16x4*)(xf + (size_t)s1 * FDIM);
    h16x4 v2 = *(const h16x4*)(xf + (size_t)s2 * FDIM);
    h16x4 v3 = *(const h16x4*)(xf + (size_t)s3 * FDIM);
    f32x4 f0 = {(float)v0.x, (float)v0.y, (float)v0.z, (float)v0.w};
    f32x4 f1 = {(float)v1.x, (float)v1.y, (float)v1.z, (float)v1.w};
    f32x4 f2 = {(float)v2.x, (float)v2.y, (float)v2.z, (float)v2.w};
    f32x4 f3 = {(float)v3.x, (float)v3.y, (float)v3.z, (float)v3.w};
    a0 += w0 * f0; a1 += w1 * f1; a2 += w2 * f2; a3 += w3 * f3;
  }
  for (; j + 2 <= m; j += 2) {
    int s0 = __shfl(s, j + g);
    float w0 = __shfl(w, j + g);
    h16x4 v0 = *(const h16x4*)(xf + (size_t)s0 * FDIM);
    f32x4 f0 = {(float)v0.x, (float)v0.y, (float)v0.z, (float)v0.w};
    a0 += w0 * f0;
  }
  if (j < m) {
    int s0 = __shfl(s, j);
    float w0 = __shfl(w, j);
    if (g == 0) {
      h16x4 v0 = *(const h16x4*)(xf + (size_t)s0 * FDIM);
      f32x4 f0 = {(float)v0.x, (float)v0.y, (float)v0.z, (float)v0.w};
      a0 += w0 * f0;
    }
  }
  f32x4 acc = (a0 + a1) + (a2 + a3);
  f32x4 o;
  o.x = __shfl_xor(acc.x, 32);
  o.y = __shfl_xor(acc.y, 32);
  o.z = __shfl_xor(acc.z, 32);
  o.w = __shfl_xor(acc.w, 32);
  acc += o;
  if (g == 0) {
    h16x4 h = {(_Float16)acc.x, (_Float16)acc.y, (_Float16)acc.z, (_Float16)acc.w};
    *(h16x4*)(out + (size_t)node * FDIM + fl * 4) = h;
  }
}

// ---------------- split-bf16 MFMA GEMM: C = act([A0|A1|A2] @ [G0;G1;G2] + b) ----------
// A inputs fp16; C -> fp16 (layers 1,2) or fp32 (layer 3, C32 != nullptr).
#define GBM 128
#define APAD 40  // LDS row stride in bf16 elems (80 B, 16B-aligned, 2-way conflicts only)
__global__ __launch_bounds__(256) void gemm3_mfma_kernel(
    const _Float16* __restrict__ A0, const _Float16* __restrict__ A1,
    const _Float16* __restrict__ A2,
    const unsigned short* __restrict__ Gh, const unsigned short* __restrict__ Gl,
    const float* __restrict__ bias, _Float16* __restrict__ C16, float* __restrict__ C32,
    int n, int layer, int do_relu) {
  __shared__ unsigned short ah_s[GBM * APAD];
  __shared__ unsigned short al_s[GBM * APAD];
  const int tid = threadIdx.x;
  const int lane = tid & 63;
  const int wave = tid >> 6;
  const int wm = wave >> 1, wn = wave & 1;
  const int bm0 = blockIdx.x * GBM;
  const int lm = lane & 15, lq = lane >> 4;

  f32x4 acc[4][4];
#pragma unroll
  for (int mt = 0; mt < 4; ++mt)
#pragma unroll
    for (int nt = 0; nt < 4; ++nt) acc[mt][nt] = (f32x4){0.f, 0.f, 0.f, 0.f};

  const _Float16* Asrc[3] = {A0, A1, A2};
#pragma unroll 1
  for (int S = 0; S < 3; ++S) {
    const _Float16* A = Asrc[S];
#pragma unroll 1
    for (int c = 0; c < 4; ++c) {
      __syncthreads();
      // stage 128 rows x 32 k of fp16 A -> bf16 hi/lo planes in LDS
#pragma unroll
      for (int i = 0; i < 4; ++i) {
        int id = tid + i * 256;
        int row = id >> 3, cg = (id & 7) * 4;
        int gr = bm0 + row; if (gr >= n) gr = n - 1;
        h16x4 v = *(const h16x4*)(A + (size_t)gr * FDIM + c * 32 + cg);
        float fx = (float)v.x, fy = (float)v.y, fz = (float)v.z, fw = (float)v.w;
        unsigned short h0 = f2bf_hi(fx), h1 = f2bf_hi(fy), h2 = f2bf_hi(fz), h3 = f2bf_hi(fw);
        unsigned short l0 = f2bf_hi(fx - bf2f(h0)), l1 = f2bf_hi(fy - bf2f(h1));
        unsigned short l2 = f2bf_hi(fz - bf2f(h2)), l3 = f2bf_hi(fw - bf2f(h3));
        unsigned long long hp = (unsigned long long)h0 | ((unsigned long long)h1 << 16) |
                                ((unsigned long long)h2 << 32) | ((unsigned long long)h3 << 48);
        unsigned long long lp = (unsigned long long)l0 | ((unsigned long long)l1 << 16) |
                                ((unsigned long long)l2 << 32) | ((unsigned long long)l3 << 48);
        *(unsigned long long*)&ah_s[row * APAD + cg] = hp;
        *(unsigned long long*)&al_s[row * APAD + cg] = lp;
      }
      __syncthreads();
      short8 ah[4], al[4];
#pragma unroll
      for (int mt = 0; mt < 4; ++mt) {
        int r = wm * 64 + mt * 16 + lm;
        ah[mt] = *(const short8*)&ah_s[r * APAD + lq * 8];
        al[mt] = *(const short8*)&al_s[r * APAD + lq * 8];
      }
      short8 bh[4], bl[4];
      size_t gb = (((size_t)(layer * 3 + S) * 4 + c) * 8) * 512;
#pragma unroll
      for (int nt = 0; nt < 4; ++nt) {
        int t = wn * 4 + nt;
        size_t o = gb + ((size_t)t * 64 + lane) * 8;
        bh[nt] = *(const short8*)(Gh + o);
        bl[nt] = *(const short8*)(Gl + o);
      }
#pragma unroll
      for (int mt = 0; mt < 4; ++mt)
#pragma unroll
        for (int nt = 0; nt < 4; ++nt) {
          acc[mt][nt] = __builtin_amdgcn_mfma_f32_16x16x32_bf16(ah[mt], bh[nt], acc[mt][nt], 0, 0, 0);
          acc[mt][nt] = __builtin_amdgcn_mfma_f32_16x16x32_bf16(ah[mt], bl[nt], acc[mt][nt], 0, 0, 0);
          acc[mt][nt] = __builtin_amdgcn_mfma_f32_16x16x32_bf16(al[mt], bh[nt], acc[mt][nt], 0, 0, 0);
        }
    }
  }
  float bv[4];
#pragma unroll
  for (int nt = 0; nt < 4; ++nt) bv[nt] = bias[wn * 64 + nt * 16 + lm];
#pragma unroll
  for (int mt = 0; mt < 4; ++mt) {
#pragma unroll
    for (int r = 0; r < 4; ++r) {
      int row = bm0 + wm * 64 + mt * 16 + lq * 4 + r;
      if (row < n) {
#pragma unroll
        for (int nt = 0; nt < 4; ++nt) {
          float v = acc[mt][nt][r] + bv[nt];
          if (do_relu) v = fmaxf(v, 0.f);
          int col = wn * 64 + nt * 16 + lm;
          if (C32) C32[(size_t)row * FDIM + col] = v;
          else     C16[(size_t)row * FDIM + col] = (_Float16)v;
        }
      }
    }
  }
}

// ---------------- pooling ----------------
__device__ __forceinline__ int lb_search(const int* __restrict__ b, int n, int val) {
  int lo = 0, hi = n;
  while (lo < hi) { int mid = (lo + hi) >> 1; if (b[mid] < val) lo = mid + 1; else hi = mid; }
  return lo;
}

__global__ void pool_kernel(const float* __restrict__ h, const int* __restrict__ batch,
                            float* __restrict__ sums, int* __restrict__ cntg, int n) {
  int g = blockIdx.x, s = blockIdx.y;
  int beg = lb_search(batch, n, g);
  int end = lb_search(batch, n, g + 1);
  if (s == 0 && threadIdx.x == 0) cntg[g] = end - beg;
  long long len = end - beg;
  int c0 = beg + (int)((len * s) / 8);
  int c1 = beg + (int)((len * (s + 1)) / 8);
  int f = threadIdx.x;  // 128 threads
  float acc = 0.f;
  for (int r = c0; r < c1; ++r) acc += h[(size_t)r * FDIM + f];
  if (c1 > c0) atomicAdd(&sums[g * FDIM + f], acc);
}

__global__ void final_kernel(const float* __restrict__ sums, const int* __restrict__ cntg,
                             const float* __restrict__ Wl, const float* __restrict__ bl,
                             float* __restrict__ out) {
  int g = blockIdx.x;
  __shared__ float row[FDIM];
  int t = threadIdx.x;  // 128 threads
  float inv = 1.f / fmaxf((float)cntg[g], 1.f);
  row[t] = sums[g * FDIM + t] * inv;
  __syncthreads();
  if (t < CLSN) {
    float a = bl[t];
#pragma unroll 4
    for (int f = 0; f < FDIM; ++f) a = fmaf(row[f], Wl[f * CLSN + t], a);
    out[g * CLSN + t] = a;
  }
}

// ---------------- launch ----------------
extern "C" void kernel_launch(void* const* d_in, const int* in_sizes, int n_in,
                              void* d_out, int out_size, void* d_ws, size_t ws_size,
                              hipStream_t stream) {
  const float* x   = (const float*)d_in[0];
  const int*   ei  = (const int*)d_in[1];
  const int* batch = (const int*)d_in[2];
  const float* W1  = (const float*)d_in[3];
  const float* b1  = (const float*)d_in[4];
  const float* W2  = (const float*)d_in[5];
  const float* b2  = (const float*)d_in[6];
  const float* W3  = (const float*)d_in[7];
  const float* b3  = (const float*)d_in[8];
  const float* Wl  = (const float*)d_in[9];
  const float* bl  = (const float*)d_in[10];
  float* out = (float*)d_out;

  const int n = in_sizes[0] / FDIM;      // 100000
  const int E = in_sizes[1] / 2;         // 1600000
  const int* esrc = ei;
  const int* edst = ei + E;

  char* ws = (char*)d_ws;
  size_t off = 0;
  auto alloc = [&](size_t bytes) -> void* {
    void* p = ws + off;
    off += (bytes + 255) & ~(size_t)255;
    return p;
  };
  const size_t NH = (size_t)n * FDIM * sizeof(_Float16);
  _Float16* Ha   = (_Float16*)alloc(NH);      // xh / H (in-place per layer)
  _Float16* Hb   = (_Float16*)alloc(NH);      // P1
  _Float16* Hc   = (_Float16*)alloc(NH);      // P2
  float*    Hf   = (float*)alloc((size_t)n * FDIM * sizeof(float));  // layer-3 out
  int2*     rows = (int2*)alloc((size_t)n * RCAP * 8);
  float*    dinv = (float*)alloc((size_t)n * 4);
  unsigned short* Gh = (unsigned short*)alloc((size_t)3 * 3 * FDIM * FDIM * 2);
  unsigned short* Gl = (unsigned short*)alloc((size_t)3 * 3 * FDIM * FDIM * 2);
  // zeroed region (one memset): deg | fillc | sums | cntg
  char*  zbase = ws + off;
  int*   deg   = (int*)alloc((size_t)n * 4);
  int*   fillc = (int*)alloc((size_t)n * 4);
  float* sums  = (float*)alloc((size_t)64 * FDIM * 4);
  int*   cntg  = (int*)alloc((size_t)64 * 4);
  size_t zsize = (size_t)((ws + off) - zbase);
  hipMemsetAsync(zbase, 0, zsize, stream);

  prep_kernel<<<(3 * 3 * FDIM * FDIM + 255) / 256, 256, 0, stream>>>(W1, W2, W3, Gh, Gl);
  deg_kernel<<<(E + 255) / 256, 256, 0, stream>>>(esrc, deg, E);
  dinv_kernel<<<(n + 255) / 256, 256, 0, stream>>>(deg, dinv, n);
  fill_kernel<<<(E + 255) / 256, 256, 0, stream>>>(esrc, edst, dinv, fillc, rows, E);
  f2h_kernel<<<((n * FDIM / 4) + 255) / 256, 256, 0, stream>>>(x, Ha, n * FDIM / 4);

  int prop_grid = (n + 3) / 4;               // 4 nodes (waves) per 256-thread block
  int gemm_grid = (n + GBM - 1) / GBM;       // 782

  // layer 1 (gemm writes H over Ha: each block touches only its own rows)
  prop_kernel<<<prop_grid, 256, 0, stream>>>(Ha, Hb, fillc, rows, n);
  prop_kernel<<<prop_grid, 256, 0, stream>>>(Hb, Hc, fillc, rows, n);
  gemm3_mfma_kernel<<<gemm_grid, 256, 0, stream>>>(Ha, Hb, Hc, Gh, Gl, b1, Ha, nullptr, n, 0, 1);

  // layer 2
  prop_kernel<<<prop_grid, 256, 0, stream>>>(Ha, Hb, fillc, rows, n);
  prop_kernel<<<prop_grid, 256, 0, stream>>>(Hb, Hc, fillc, rows, n);
  gemm3_mfma_kernel<<<gemm_grid, 256, 0, stream>>>(Ha, Hb, Hc, Gh, Gl, b2, Ha, nullptr, n, 1, 1);

  // layer 3: fp32 out, no relu
  prop_kernel<<<prop_grid, 256, 0, stream>>>(Ha, Hb, fillc, rows, n);
  prop_kernel<<<prop_grid, 256, 0, stream>>>(Hb, Hc, fillc, rows, n);
  gemm3_mfma_kernel<<<gemm_grid, 256, 0, stream>>>(Ha, Hb, Hc, Gh, Gl, b3, nullptr, Hf, n, 2, 0);

  // pool + classifier
  pool_kernel<<<dim3(64, 8), 128, 0, stream>>>(Hf, batch, sums, cntg, n);
  final_kernel<<<64, 128, 0, stream>>>(sums, cntg, Wl, bl, out);
}

// Round 5
// 886.651 us; speedup vs baseline: 2.4686x; 1.0010x over previous
//
#include <hip/hip_runtime.h>
#include <cstdint>
#include <cstddef>

#define FDIM 128
#define CLSN 10
#define RCAP 64

typedef __attribute__((ext_vector_type(4))) float f32x4;
typedef __attribute__((ext_vector_type(4))) _Float16 h16x4;
typedef __attribute__((ext_vector_type(8))) _Float16 h16x8;

// ---------------- merged graph build: out-degree + padded CSR fill ----------------
__global__ void build_kernel(const int* __restrict__ src, const int* __restrict__ dst,
                             int* __restrict__ deg, int* __restrict__ fillc,
                             int* __restrict__ rows, int E) {
  int e = blockIdx.x * blockDim.x + threadIdx.x;
  if (e < E) {
    int s = src[e], d = dst[e];
    atomicAdd(&deg[s], 1);
    int pos = atomicAdd(&fillc[d], 1);
    if (pos < RCAP) rows[(size_t)d * RCAP + pos] = s;
  }
}

__global__ void dinv_kernel(const int* __restrict__ deg, float* __restrict__ dinv, int n) {
  int i = blockIdx.x * blockDim.x + threadIdx.x;
  if (i < n) {
    int d = deg[i];
    dinv[i] = d > 0 ? rsqrtf((float)d) : 0.0f;
  }
}

// ---------------- fp32 -> fp16 convert (vectorized x4) ----------------
__global__ void f2h_kernel(const float* __restrict__ in, _Float16* __restrict__ out, int n4) {
  int i = blockIdx.x * blockDim.x + threadIdx.x;
  if (i < n4) {
    float4 v = *(const float4*)(in + (size_t)i * 4);
    h16x4 h = {(_Float16)v.x, (_Float16)v.y, (_Float16)v.z, (_Float16)v.w};
    *(h16x4*)(out + (size_t)i * 4) = h;
  }
}

// ---------------- weight prep: combine, split fp16 hi/lo, swizzle to B-frag order ----
// Layout: idx = ((((L*3+S)*4 + c)*8 + t)*64 + lane)*8 + j
//   where k = c*32 + (lane>>4)*8 + j, col = t*16 + (lane&15)
__global__ void prep_kernel(const float* __restrict__ W1, const float* __restrict__ W2,
                            const float* __restrict__ W3,
                            _Float16* __restrict__ Gh, _Float16* __restrict__ Gl) {
  const int MS = FDIM * FDIM;
  int idx = blockIdx.x * blockDim.x + threadIdx.x;
  if (idx >= 3 * 3 * MS) return;
  int L = idx / (3 * MS);
  int rem = idx - L * 3 * MS;
  int S = rem / MS;
  int e = rem - S * MS;            // e = k*128 + nn
  int k = e >> 7, nn = e & 127;
  const float* W = (L == 0) ? W1 : (L == 1) ? W2 : W3;
  float w0 = W[e], w1 = W[MS + e], w2 = W[2 * MS + e];
  float v = (S == 0) ? (w0 - w2) : (S == 1) ? w1 : (2.f * w2);
  _Float16 hi = (_Float16)v;
  _Float16 lo = (_Float16)(v - (float)hi);
  int c = k >> 5, q = (k >> 3) & 3, j = k & 7;
  int t = nn >> 4, nl = nn & 15;
  int lane = q * 16 + nl;
  size_t out = ((((size_t)(L * 3 + S) * 4 + c) * 8 + t) * 64 + lane) * 8 + j;
  Gh[out] = hi;
  Gl[out] = lo;
}

// ---------------- propagation: out[d] = -dinv[d] * sum_e dinv[src_e] * x[src_e] -------
// one wave per dst node; 4 groups x 16 lanes, lane = 8 features (16 B h16x8).
// 2 independent edge chains per group + 1-iter prefetch of (src, dinv); no shfl in loop.
__global__ __launch_bounds__(256) void prop_kernel(
    const _Float16* __restrict__ x, _Float16* __restrict__ out,
    const int* __restrict__ rcnt, const int* __restrict__ rows,
    const float* __restrict__ dinv, int n) {
  int node = (int)(((size_t)blockIdx.x * blockDim.x + threadIdx.x) >> 6);
  int lane = threadIdx.x & 63;
  if (node >= n) return;
  const int g = lane >> 4, fl = lane & 15;
  int m = rcnt[node]; if (m > RCAP) m = RCAP;
  const int* __restrict__ row = rows + (size_t)node * RCAP;
  const _Float16* __restrict__ xf = x + fl * 8;
  float acc[8];
#pragma unroll
  for (int j = 0; j < 8; ++j) acc[j] = 0.f;

  int eA = g, eB = g + 4;
  int sA = 0, sB = 0;
  float dA = 0.f, dB = 0.f;
  if (m > 0) {
    sA = row[min(eA, m - 1)];
    sB = row[min(eB, m - 1)];
    dA = (eA < m) ? dinv[sA] : 0.f;
    dB = (eB < m) ? dinv[sB] : 0.f;
  }
  while (eA < m) {
    int eA2 = eA + 8, eB2 = eB + 8;
    int sA2 = row[min(eA2, m - 1)];
    int sB2 = row[min(eB2, m - 1)];
    float dA2 = (eA2 < m) ? dinv[sA2] : 0.f;
    float dB2 = (eB2 < m) ? dinv[sB2] : 0.f;
    h16x8 va = *(const h16x8*)(xf + (size_t)sA * FDIM);
    h16x8 vb = *(const h16x8*)(xf + (size_t)sB * FDIM);
#pragma unroll
    for (int j = 0; j < 8; ++j)
      acc[j] = fmaf(dA, (float)va[j], fmaf(dB, (float)vb[j], acc[j]));
    eA = eA2; eB = eB2; sA = sA2; sB = sB2; dA = dA2; dB = dB2;
  }
  // reduce across the 4 groups (lanes with same fl)
#pragma unroll
  for (int j = 0; j < 8; ++j) {
    acc[j] += __shfl_xor(acc[j], 16);
    acc[j] += __shfl_xor(acc[j], 32);
  }
  if (lane < 16) {
    float sc = -dinv[node];
    h16x8 h;
#pragma unroll
    for (int j = 0; j < 8; ++j) h[j] = (_Float16)(sc * acc[j]);
    *(h16x8*)(out + (size_t)node * FDIM + fl * 8) = h;
  }
}

// ---------------- f16 MFMA GEMM: C = act([A0|A1|A2] @ [G0;G1;G2] + b) ----------------
// A fp16 (native f16 MFMA operand, lossless); B split fp16 hi/lo (residual 2^-22).
// Block: 256 threads (4 waves, 2x2), tile 128x128. K chunks of 32. 2 MFMAs/tile.
#define GBM 128
#define APAD 40  // LDS row stride in fp16 elems (80 B): stride-20-word pattern -> 2-way max
__global__ __launch_bounds__(256) void gemm3_mfma_kernel(
    const _Float16* __restrict__ A0, const _Float16* __restrict__ A1,
    const _Float16* __restrict__ A2,
    const _Float16* __restrict__ Gh, const _Float16* __restrict__ Gl,
    const float* __restrict__ bias, _Float16* __restrict__ C16, float* __restrict__ C32,
    int n, int layer, int do_relu) {
  __shared__ _Float16 a_s[GBM * APAD];
  const int tid = threadIdx.x;
  const int lane = tid & 63;
  const int wave = tid >> 6;
  const int wm = wave >> 1, wn = wave & 1;
  const int bm0 = blockIdx.x * GBM;
  const int lm = lane & 15, lq = lane >> 4;

  f32x4 acc[4][4];
#pragma unroll
  for (int mt = 0; mt < 4; ++mt)
#pragma unroll
    for (int nt = 0; nt < 4; ++nt) acc[mt][nt] = (f32x4){0.f, 0.f, 0.f, 0.f};

  const _Float16* Asrc[3] = {A0, A1, A2};
#pragma unroll 1
  for (int S = 0; S < 3; ++S) {
    const _Float16* A = Asrc[S];
#pragma unroll 1
    for (int c = 0; c < 4; ++c) {
      __syncthreads();
      // stage 128 rows x 32 k of fp16 A (8 KB) via 2 x 16B per thread
#pragma unroll
      for (int i = 0; i < 2; ++i) {
        int id = tid + i * 256;
        int row = id >> 2, cg = (id & 3) * 8;
        int gr = bm0 + row; if (gr >= n) gr = n - 1;
        h16x8 v = *(const h16x8*)(A + (size_t)gr * FDIM + c * 32 + cg);
        *(h16x8*)&a_s[row * APAD + cg] = v;
      }
      __syncthreads();
      h16x8 af[4];
#pragma unroll
      for (int mt = 0; mt < 4; ++mt) {
        int r = wm * 64 + mt * 16 + lm;
        af[mt] = *(const h16x8*)&a_s[r * APAD + lq * 8];
      }
      h16x8 bh[4], bl[4];
      size_t gb = (((size_t)(layer * 3 + S) * 4 + c) * 8) * 512;
#pragma unroll
      for (int nt = 0; nt < 4; ++nt) {
        int t = wn * 4 + nt;
        size_t o = gb + ((size_t)t * 64 + lane) * 8;
        bh[nt] = *(const h16x8*)(Gh + o);
        bl[nt] = *(const h16x8*)(Gl + o);
      }
#pragma unroll
      for (int mt = 0; mt < 4; ++mt)
#pragma unroll
        for (int nt = 0; nt < 4; ++nt) {
          acc[mt][nt] = __builtin_amdgcn_mfma_f32_16x16x32_f16(af[mt], bh[nt], acc[mt][nt], 0, 0, 0);
          acc[mt][nt] = __builtin_amdgcn_mfma_f32_16x16x32_f16(af[mt], bl[nt], acc[mt][nt], 0, 0, 0);
        }
    }
  }
  float bv[4];
#pragma unroll
  for (int nt = 0; nt < 4; ++nt) bv[nt] = bias[wn * 64 + nt * 16 + lm];
#pragma unroll
  for (int mt = 0; mt < 4; ++mt) {
#pragma unroll
    for (int r = 0; r < 4; ++r) {
      int row = bm0 + wm * 64 + mt * 16 + lq * 4 + r;
      if (row < n) {
#pragma unroll
        for (int nt = 0; nt < 4; ++nt) {
          float v = acc[mt][nt][r] + bv[nt];
          if (do_relu) v = fmaxf(v, 0.f);
          int col = wn * 64 + nt * 16 + lm;
          if (C32) C32[(size_t)row * FDIM + col] = v;
          else     C16[(size_t)row * FDIM + col] = (_Float16)v;
        }
      }
    }
  }
}

// ---------------- pooling ----------------
__device__ __forceinline__ int lb_search(const int* __restrict__ b, int n, int val) {
  int lo = 0, hi = n;
  while (lo < hi) { int mid = (lo + hi) >> 1; if (b[mid] < val) lo = mid + 1; else hi = mid; }
  return lo;
}

__global__ void pool_kernel(const float* __restrict__ h, const int* __restrict__ batch,
                            float* __restrict__ sums, int* __restrict__ cntg, int n) {
  int g = blockIdx.x, s = blockIdx.y;
  int beg = lb_search(batch, n, g);
  int end = lb_search(batch, n, g + 1);
  if (s == 0 && threadIdx.x == 0) cntg[g] = end - beg;
  long long len = end - beg;
  int c0 = beg + (int)((len * s) / 8);
  int c1 = beg + (int)((len * (s + 1)) / 8);
  int f = threadIdx.x;  // 128 threads
  float acc = 0.f;
  for (int r = c0; r < c1; ++r) acc += h[(size_t)r * FDIM + f];
  if (c1 > c0) atomicAdd(&sums[g * FDIM + f], acc);
}

__global__ void final_kernel(const float* __restrict__ sums, const int* __restrict__ cntg,
                             const float* __restrict__ Wl, const float* __restrict__ bl,
                             float* __restrict__ out) {
  int g = blockIdx.x;
  __shared__ float row[FDIM];
  int t = threadIdx.x;  // 128 threads
  float inv = 1.f / fmaxf((float)cntg[g], 1.f);
  row[t] = sums[g * FDIM + t] * inv;
  __syncthreads();
  if (t < CLSN) {
    float a = bl[t];
#pragma unroll 4
    for (int f = 0; f < FDIM; ++f) a = fmaf(row[f], Wl[f * CLSN + t], a);
    out[g * CLSN + t] = a;
  }
}

// ---------------- launch ----------------
extern "C" void kernel_launch(void* const* d_in, const int* in_sizes, int n_in,
                              void* d_out, int out_size, void* d_ws, size_t ws_size,
                              hipStream_t stream) {
  const float* x   = (const float*)d_in[0];
  const int*   ei  = (const int*)d_in[1];
  const int* batch = (const int*)d_in[2];
  const float* W1  = (const float*)d_in[3];
  const float* b1  = (const float*)d_in[4];
  const float* W2  = (const float*)d_in[5];
  const float* b2  = (const float*)d_in[6];
  const float* W3  = (const float*)d_in[7];
  const float* b3  = (const float*)d_in[8];
  const float* Wl  = (const float*)d_in[9];
  const float* bl  = (const float*)d_in[10];
  float* out = (float*)d_out;

  const int n = in_sizes[0] / FDIM;      // 100000
  const int E = in_sizes[1] / 2;         // 1600000
  const int* esrc = ei;
  const int* edst = ei + E;

  char* ws = (char*)d_ws;
  size_t off = 0;
  auto alloc = [&](size_t bytes) -> void* {
    void* p = ws + off;
    off += (bytes + 255) & ~(size_t)255;
    return p;
  };
  const size_t NH = (size_t)n * FDIM * sizeof(_Float16);
  _Float16* Ha   = (_Float16*)alloc(NH);      // xh / H (in-place per layer)
  _Float16* Hb   = (_Float16*)alloc(NH);      // P1
  _Float16* Hc   = (_Float16*)alloc(NH);      // P2
  float*    Hf   = (float*)alloc((size_t)n * FDIM * sizeof(float));  // layer-3 out
  int*      rows = (int*)alloc((size_t)n * RCAP * 4);
  float*    dinv = (float*)alloc((size_t)n * 4);
  _Float16* Gh   = (_Float16*)alloc((size_t)3 * 3 * FDIM * FDIM * 2);
  _Float16* Gl   = (_Float16*)alloc((size_t)3 * 3 * FDIM * FDIM * 2);
  // zeroed region (one memset): deg | fillc | sums | cntg
  char*  zbase = ws + off;
  int*   deg   = (int*)alloc((size_t)n * 4);
  int*   fillc = (int*)alloc((size_t)n * 4);
  float* sums  = (float*)alloc((size_t)64 * FDIM * 4);
  int*   cntg  = (int*)alloc((size_t)64 * 4);
  size_t zsize = (size_t)((ws + off) - zbase);
  hipMemsetAsync(zbase, 0, zsize, stream);

  prep_kernel<<<(3 * 3 * FDIM * FDIM + 255) / 256, 256, 0, stream>>>(W1, W2, W3, Gh, Gl);
  build_kernel<<<(E + 255) / 256, 256, 0, stream>>>(esrc, edst, deg, fillc, rows, E);
  dinv_kernel<<<(n + 255) / 256, 256, 0, stream>>>(deg, dinv, n);
  f2h_kernel<<<((n * FDIM / 4) + 255) / 256, 256, 0, stream>>>(x, Ha, n * FDIM / 4);

  int prop_grid = (n + 3) / 4;               // 4 nodes (waves) per 256-thread block
  int gemm_grid = (n + GBM - 1) / GBM;       // 782

  // layer 1 (gemm writes H over Ha: each block touches only its own rows)
  prop_kernel<<<prop_grid, 256, 0, stream>>>(Ha, Hb, fillc, rows, dinv, n);
  prop_kernel<<<prop_grid, 256, 0, stream>>>(Hb, Hc, fillc, rows, dinv, n);
  gemm3_mfma_kernel<<<gemm_grid, 256, 0, stream>>>(Ha, Hb, Hc, Gh, Gl, b1, Ha, nullptr, n, 0, 1);

  // layer 2
  prop_kernel<<<prop_grid, 256, 0, stream>>>(Ha, Hb, fillc, rows, dinv, n);
  prop_kernel<<<prop_grid, 256, 0, stream>>>(Hb, Hc, fillc, rows, dinv, n);
  gemm3_mfma_kernel<<<gemm_grid, 256, 0, stream>>>(Ha, Hb, Hc, Gh, Gl, b2, Ha, nullptr, n, 1, 1);

  // layer 3: fp32 out, no relu
  prop_kernel<<<prop_grid, 256, 0, stream>>>(Ha, Hb, fillc, rows, dinv, n);
  prop_kernel<<<prop_grid, 256, 0, stream>>>(Hb, Hc, fillc, rows, dinv, n);
  gemm3_mfma_kernel<<<gemm_grid, 256, 0, stream>>>(Ha, Hb, Hc, Gh, Gl, b3, nullptr, Hf, n, 2, 0);

  // pool + classifier
  pool_kernel<<<dim3(64, 8), 128, 0, stream>>>(Hf, batch, sums, cntg, n);
  final_kernel<<<64, 128, 0, stream>>>(sums, cntg, Wl, bl, out);
}